// Round 2
// baseline (7506.504 us; speedup 1.0000x reference)
//
#include <hip/hip_runtime.h>
#include <cfloat>
#include <cstdint>

#define D_IN  2048
#define D_HID 16384
#define TOPK  16
#define CAND  32          // coarse candidate superset size
#define BATCH 4096

// ---------------------------------------------------------------------------
// Encode GEMM (coarse): y[M, D_HID] = x[M, D_IN] * W[D_HID, D_IN]^T + b
// fp32 vector-ALU tiled GEMM. 128x128 block tile, 8x8 per thread, BK=8.
// Only needs to be accurate enough that the true top-16 lands in the
// per-row top-32 (margin ~0.3 vs error ~1e-5).
// ---------------------------------------------------------------------------
#define TM 128
#define TN 128
#define BKK 8

__global__ __launch_bounds__(256) void encode_gemm(
    const float* __restrict__ A,      // [chunkM, D_IN], row-major
    const float* __restrict__ B,      // [D_HID, D_IN], row-major (w_enc_w)
    const float* __restrict__ bias,   // [D_HID]
    float* __restrict__ C)            // [chunkM, D_HID]
{
    __shared__ float As[BKK][TM];
    __shared__ float Bs[BKK][TN];

    const int tid = threadIdx.x;
    const int tx = tid & 15;
    const int ty = tid >> 4;
    const int rowBase = blockIdx.y * TM;
    const int colBase = blockIdx.x * TN;

    const int lr = tid >> 1;           // 0..127
    const int lk = (tid & 1) * 4;      // 0 or 4

    const float* Aload = A + (size_t)(rowBase + lr) * D_IN + lk;
    const float* Bload = B + (size_t)(colBase + lr) * D_IN + lk;

    float acc[8][8];
#pragma unroll
    for (int i = 0; i < 8; ++i)
#pragma unroll
        for (int j = 0; j < 8; ++j) acc[i][j] = 0.f;

    for (int k0 = 0; k0 < D_IN; k0 += BKK) {
        float4 av = *(const float4*)(Aload + k0);
        float4 bv = *(const float4*)(Bload + k0);
        __syncthreads();
        As[lk + 0][lr] = av.x; As[lk + 1][lr] = av.y;
        As[lk + 2][lr] = av.z; As[lk + 3][lr] = av.w;
        Bs[lk + 0][lr] = bv.x; Bs[lk + 1][lr] = bv.y;
        Bs[lk + 2][lr] = bv.z; Bs[lk + 3][lr] = bv.w;
        __syncthreads();
#pragma unroll
        for (int kk = 0; kk < BKK; ++kk) {
            float4 a0 = *(const float4*)&As[kk][ty * 8];
            float4 a1 = *(const float4*)&As[kk][ty * 8 + 4];
            float4 b0 = *(const float4*)&Bs[kk][tx * 4];
            float4 b1 = *(const float4*)&Bs[kk][64 + tx * 4];
            float a[8] = {a0.x, a0.y, a0.z, a0.w, a1.x, a1.y, a1.z, a1.w};
            float b[8] = {b0.x, b0.y, b0.z, b0.w, b1.x, b1.y, b1.z, b1.w};
#pragma unroll
            for (int i = 0; i < 8; ++i)
#pragma unroll
                for (int j = 0; j < 8; ++j)
                    acc[i][j] += a[i] * b[j];
        }
    }

    float4 bb0 = *(const float4*)(bias + colBase + tx * 4);
    float4 bb1 = *(const float4*)(bias + colBase + 64 + tx * 4);

#pragma unroll
    for (int i = 0; i < 8; ++i) {
        const size_t rowOff = (size_t)(rowBase + ty * 8 + i) * D_HID + colBase;
        float4 o0 = {acc[i][0] + bb0.x, acc[i][1] + bb0.y,
                     acc[i][2] + bb0.z, acc[i][3] + bb0.w};
        float4 o1 = {acc[i][4] + bb1.x, acc[i][5] + bb1.y,
                     acc[i][6] + bb1.z, acc[i][7] + bb1.w};
        *(float4*)(C + rowOff + tx * 4)      = o0;
        *(float4*)(C + rowOff + 64 + tx * 4) = o1;
    }
}

// ---------------------------------------------------------------------------
// Coarse Top-CAND per row: per-thread register top-32 (ascending-index scan,
// strict-> insertion) then CAND rounds of block argmax (value desc, idx asc).
// Superset only — exact ordering resolved by the fp64 refine pass.
// ---------------------------------------------------------------------------
__global__ __launch_bounds__(256) void topk_kernel(
    const float* __restrict__ y,       // [chunkM, D_HID]
    float* __restrict__ cvals,         // [BATCH, CAND]
    int* __restrict__ cidxs,           // [BATCH, CAND]
    int rowBase)
{
    __shared__ float rv[256];
    __shared__ int   ri[256];

    const int tid = threadIdx.x;
    const int row = rowBase + blockIdx.x;
    const float4* yr4 = (const float4*)(y + (size_t)blockIdx.x * D_HID);

    float lv[CAND];
    int   li[CAND];
#pragma unroll
    for (int t = 0; t < CAND; ++t) { lv[t] = -FLT_MAX; li[t] = 0x7FFFFFFF; }

    for (int j = 0; j < 16; ++j) {
        const int i4 = tid + j * 256;
        float4 v4 = yr4[i4];
        float vv[4] = {v4.x, v4.y, v4.z, v4.w};
#pragma unroll
        for (int c = 0; c < 4; ++c) {
            float cvv = vv[c];
            if (cvv > lv[CAND - 1]) {
                int cii = i4 * 4 + c;
#pragma unroll
                for (int t = 0; t < CAND; ++t) {
                    if (cvv > lv[t]) {
                        float tv = lv[t]; lv[t] = cvv; cvv = tv;
                        int   ti = li[t]; li[t] = cii; cii = ti;
                    }
                }
            }
        }
    }

    for (int k = 0; k < CAND; ++k) {
        float bv = -FLT_MAX; int bi = 0x7FFFFFFF;
#pragma unroll
        for (int t = 0; t < CAND; ++t) {
            if (lv[t] > bv || (lv[t] == bv && li[t] < bi)) { bv = lv[t]; bi = li[t]; }
        }
        rv[tid] = bv; ri[tid] = bi;
        __syncthreads();
        for (int s = 128; s > 0; s >>= 1) {
            if (tid < s) {
                float v2 = rv[tid + s]; int i2 = ri[tid + s];
                if (v2 > rv[tid] || (v2 == rv[tid] && i2 < ri[tid])) {
                    rv[tid] = v2; ri[tid] = i2;
                }
            }
            __syncthreads();
        }
        const float wv = rv[0];
        const int   wi = ri[0];
        if (tid == 0) {
            cvals[(size_t)row * CAND + k] = wv;
            cidxs[(size_t)row * CAND + k] = wi;
        }
#pragma unroll
        for (int t = 0; t < CAND; ++t) {
            if (li[t] == wi) lv[t] = -FLT_MAX;
        }
        __syncthreads();
    }
}

// ---------------------------------------------------------------------------
// fp64 refinement: recompute the CAND candidate dot products exactly, rank
// (value desc, idx asc), emit final top-16 vals (fp32) + idxs.
// One block per row; 4 waves, each wave handles CAND/4 candidates.
// ---------------------------------------------------------------------------
__global__ __launch_bounds__(256) void refine_kernel(
    const float* __restrict__ x,       // [BATCH, D_IN]
    const float* __restrict__ W,       // [D_HID, D_IN]
    const float* __restrict__ bias,    // [D_HID]
    const int* __restrict__ cidxs,     // [BATCH, CAND]
    float* __restrict__ vals,          // [BATCH, TOPK]
    int* __restrict__ idxs)            // [BATCH, TOPK]
{
    __shared__ float  sx[D_IN];        // 8 KB
    __shared__ double sdot[CAND];
    __shared__ int    scand[CAND];

    const int b = blockIdx.x;
    const int tid = threadIdx.x;

    for (int d = tid; d < D_IN; d += 256) sx[d] = x[(size_t)b * D_IN + d];
    if (tid < CAND) scand[tid] = cidxs[(size_t)b * CAND + tid];
    __syncthreads();

    const int wave = tid >> 6;
    const int lane = tid & 63;
    for (int c = wave; c < CAND; c += 4) {
        const int h = scand[c];
        const float* wr = W + (size_t)h * D_IN;
        double acc = 0.0;
        for (int d = lane; d < D_IN; d += 64)
            acc += (double)sx[d] * (double)wr[d];
#pragma unroll
        for (int off = 32; off > 0; off >>= 1)
            acc += __shfl_down(acc, off, 64);
        if (lane == 0) sdot[c] = acc + (double)bias[h];
    }
    __syncthreads();

    if (tid == 0) {
        double lv[CAND]; int li[CAND];
#pragma unroll
        for (int c = 0; c < CAND; ++c) { lv[c] = sdot[c]; li[c] = scand[c]; }
        for (int k = 0; k < TOPK; ++k) {
            int bi = 0;
            for (int c = 1; c < CAND; ++c) {
                if (lv[c] > lv[bi] || (lv[c] == lv[bi] && li[c] < li[bi])) bi = c;
            }
            vals[(size_t)b * TOPK + k] = (float)lv[bi];
            idxs[(size_t)b * TOPK + k] = li[bi];
            lv[bi] = -1.0e300;
        }
    }
}

// ---------------------------------------------------------------------------
// Decode: out[b, :] = sum_k vals[b,k] * W[idx[b,k], :]   (W = w_enc_w)
// Also writes idx as float into the second output region.
// ---------------------------------------------------------------------------
__global__ __launch_bounds__(256) void decode_kernel(
    const float* __restrict__ vals,
    const int* __restrict__ idxs,
    const float* __restrict__ W,       // [D_HID, D_IN] row-major
    float* __restrict__ out,           // [BATCH, D_IN]
    float* __restrict__ idxOut)        // [BATCH, TOPK] as float
{
    __shared__ float sv[TOPK];
    __shared__ int   si[TOPK];
    const int b = blockIdx.x;
    const int tid = threadIdx.x;

    if (tid < TOPK) {
        float vv = vals[(size_t)b * TOPK + tid];
        int   ii = idxs[(size_t)b * TOPK + tid];
        sv[tid] = vv; si[tid] = ii;
        idxOut[(size_t)b * TOPK + tid] = (float)ii;
    }
    __syncthreads();

    const float4* W4 = (const float4*)W;
    float4* out4 = (float4*)(out + (size_t)b * D_IN);
    for (int d4 = tid; d4 < D_IN / 4; d4 += 256) {
        float4 acc = {0.f, 0.f, 0.f, 0.f};
#pragma unroll
        for (int k = 0; k < TOPK; ++k) {
            float4 w = W4[(size_t)si[k] * (D_IN / 4) + d4];
            float s = sv[k];
            acc.x += s * w.x; acc.y += s * w.y;
            acc.z += s * w.z; acc.w += s * w.w;
        }
        out4[d4] = acc;
    }
}

// ---------------------------------------------------------------------------
extern "C" void kernel_launch(void* const* d_in, const int* in_sizes, int n_in,
                              void* d_out, int out_size, void* d_ws, size_t ws_size,
                              hipStream_t stream)
{
    const float* x    = (const float*)d_in[0];  // [BATCH, D_IN]
    const float* Wenc = (const float*)d_in[1];  // [D_HID, D_IN]
    const float* bias = (const float*)d_in[2];  // [D_HID]
    // d_in[3] = w_emb_w [D_IN, D_HID] — mathematically Wenc^T, unused.

    float* out    = (float*)d_out;                   // output 0: [BATCH, D_IN] fp32
    float* idxOut = out + (size_t)BATCH * D_IN;      // output 1: [BATCH, TOPK] as fp32

    char*  ws    = (char*)d_ws;
    float* cvals = (float*)ws;                                       // BATCH*CAND f32
    int*   cidxs = (int*)(ws + (size_t)BATCH * CAND * 4);            // BATCH*CAND i32
    float* vals  = (float*)(ws + 2 * (size_t)BATCH * CAND * 4);      // BATCH*TOPK f32
    int*   idxs  = (int*)(ws + 2 * (size_t)BATCH * CAND * 4
                             + (size_t)BATCH * TOPK * 4);            // BATCH*TOPK i32
    const size_t head = 2 * (size_t)BATCH * CAND * 4
                      + 2 * (size_t)BATCH * TOPK * 4;
    float* ybuf = (float*)(ws + head);

    int chunk = BATCH;
    while (chunk > TM && head + (size_t)chunk * D_HID * 4 > ws_size) chunk >>= 1;

    for (int r0 = 0; r0 < BATCH; r0 += chunk) {
        dim3 g(D_HID / TN, chunk / TM);
        encode_gemm<<<g, 256, 0, stream>>>(x + (size_t)r0 * D_IN, Wenc, bias, ybuf);
        topk_kernel<<<chunk, 256, 0, stream>>>(ybuf, cvals, cidxs, r0);
    }
    refine_kernel<<<BATCH, 256, 0, stream>>>(x, Wenc, bias, cidxs, vals, idxs);
    decode_kernel<<<BATCH, 256, 0, stream>>>(vals, idxs, Wenc, out, idxOut);
}

// Round 3
// 3829.855 us; speedup vs baseline: 1.9600x; 1.9600x over previous
//
#include <hip/hip_runtime.h>
#include <cfloat>
#include <cstdint>

#define D_IN  2048
#define D_HID 16384
#define TOPK  16
#define BATCH 4096

#define NBINS    4096      // 12-bit histogram: sign + 8 exp + 3 mantissa bits
#define BINSHIFT 20        // key >> 20 -> bin
#define CBUF     512       // candidate cap per row
#define TARGET   24        // min candidates above threshold (margin over 16)

// ---------------------------------------------------------------------------
// Encode GEMM (coarse): y[M, D_HID] = x[M, D_IN] * W[D_HID, D_IN]^T + b
// fp32 vector-ALU tiled GEMM. Only needs enough accuracy that the true
// top-16 lands above the coarse rank-24 threshold (margin ~0.1 vs err ~1e-5).
// ---------------------------------------------------------------------------
#define TM 128
#define TN 128
#define BKK 8

__global__ __launch_bounds__(256) void encode_gemm(
    const float* __restrict__ A,      // [chunkM, D_IN]
    const float* __restrict__ B,      // [D_HID, D_IN] (w_enc_w)
    const float* __restrict__ bias,   // [D_HID]
    float* __restrict__ C)            // [chunkM, D_HID]
{
    __shared__ float As[BKK][TM];
    __shared__ float Bs[BKK][TN];

    const int tid = threadIdx.x;
    const int tx = tid & 15;
    const int ty = tid >> 4;
    const int rowBase = blockIdx.y * TM;
    const int colBase = blockIdx.x * TN;

    const int lr = tid >> 1;
    const int lk = (tid & 1) * 4;

    const float* Aload = A + (size_t)(rowBase + lr) * D_IN + lk;
    const float* Bload = B + (size_t)(colBase + lr) * D_IN + lk;

    float acc[8][8];
#pragma unroll
    for (int i = 0; i < 8; ++i)
#pragma unroll
        for (int j = 0; j < 8; ++j) acc[i][j] = 0.f;

    for (int k0 = 0; k0 < D_IN; k0 += BKK) {
        float4 av = *(const float4*)(Aload + k0);
        float4 bv = *(const float4*)(Bload + k0);
        __syncthreads();
        As[lk + 0][lr] = av.x; As[lk + 1][lr] = av.y;
        As[lk + 2][lr] = av.z; As[lk + 3][lr] = av.w;
        Bs[lk + 0][lr] = bv.x; Bs[lk + 1][lr] = bv.y;
        Bs[lk + 2][lr] = bv.z; Bs[lk + 3][lr] = bv.w;
        __syncthreads();
#pragma unroll
        for (int kk = 0; kk < BKK; ++kk) {
            float4 a0 = *(const float4*)&As[kk][ty * 8];
            float4 a1 = *(const float4*)&As[kk][ty * 8 + 4];
            float4 b0 = *(const float4*)&Bs[kk][tx * 4];
            float4 b1 = *(const float4*)&Bs[kk][64 + tx * 4];
            float a[8] = {a0.x, a0.y, a0.z, a0.w, a1.x, a1.y, a1.z, a1.w};
            float b[8] = {b0.x, b0.y, b0.z, b0.w, b1.x, b1.y, b1.z, b1.w};
#pragma unroll
            for (int i = 0; i < 8; ++i)
#pragma unroll
                for (int j = 0; j < 8; ++j)
                    acc[i][j] += a[i] * b[j];
        }
    }

    float4 bb0 = *(const float4*)(bias + colBase + tx * 4);
    float4 bb1 = *(const float4*)(bias + colBase + 64 + tx * 4);

#pragma unroll
    for (int i = 0; i < 8; ++i) {
        const size_t rowOff = (size_t)(rowBase + ty * 8 + i) * D_HID + colBase;
        float4 o0 = {acc[i][0] + bb0.x, acc[i][1] + bb0.y,
                     acc[i][2] + bb0.z, acc[i][3] + bb0.w};
        float4 o1 = {acc[i][4] + bb1.x, acc[i][5] + bb1.y,
                     acc[i][6] + bb1.z, acc[i][7] + bb1.w};
        *(float4*)(C + rowOff + tx * 4)      = o0;
        *(float4*)(C + rowOff + 64 + tx * 4) = o1;
    }
}

// ---------------------------------------------------------------------------
// Histogram threshold select: per row, emit an UNORDERED superset of the
// top-TARGET coarse elements (exact ranking done by refine_kernel).
// key = monotonic uint transform of fp32 (descending value = descending key).
// ---------------------------------------------------------------------------
__device__ __forceinline__ unsigned f2key(float f) {
    unsigned u = __float_as_uint(f);
    return (u & 0x80000000u) ? ~u : (u | 0x80000000u);
}

__global__ __launch_bounds__(256) void topk_select(
    const float* __restrict__ y,       // [chunkM, D_HID]
    int* __restrict__ cand,            // [BATCH, CBUF]
    int* __restrict__ ccount,          // [BATCH]
    int rowBase)
{
    __shared__ unsigned hist[NBINS];   // 16 KB
    __shared__ unsigned psuf[257];
    __shared__ int sBstar;
    __shared__ unsigned scnt;

    const int tid = threadIdx.x;
    const int row = rowBase + blockIdx.x;
    const float4* yr4 = (const float4*)(y + (size_t)blockIdx.x * D_HID);

    for (int i = tid; i < NBINS; i += 256) hist[i] = 0;
    if (tid == 0) { sBstar = 0; scnt = 0; }
    __syncthreads();

    // Pass 1: histogram of top 12 key bits
    for (int j = 0; j < 16; ++j) {
        float4 v4 = yr4[tid + j * 256];
        atomicAdd(&hist[f2key(v4.x) >> BINSHIFT], 1u);
        atomicAdd(&hist[f2key(v4.y) >> BINSHIFT], 1u);
        atomicAdd(&hist[f2key(v4.z) >> BINSHIFT], 1u);
        atomicAdd(&hist[f2key(v4.w) >> BINSHIFT], 1u);
    }
    __syncthreads();

    // partial sums: thread t owns bins [t*16, t*16+16)
    {
        unsigned s = 0;
#pragma unroll
        for (int i = 0; i < 16; ++i) s += hist[tid * 16 + i];
        psuf[tid] = s;
    }
    __syncthreads();
    if (tid == 0) {
        unsigned run = 0;
        for (int t = 255; t >= 0; --t) { run += psuf[t]; psuf[t] = run; }
        psuf[256] = 0;
    }
    __syncthreads();
    // find B* = max bin with cum(B) >= TARGET  (cum(B) = #elems with bin >= B)
    {
        unsigned run = psuf[tid + 1];
        for (int b = tid * 16 + 15; b >= tid * 16; --b) {
            run += hist[b];
            if (run >= TARGET) { atomicMax(&sBstar, b); break; }
        }
    }
    __syncthreads();
    const unsigned keyT = ((unsigned)sBstar) << BINSHIFT;

    // Pass 2: compact candidate indices (unordered)
    for (int j = 0; j < 16; ++j) {
        const int i4 = tid + j * 256;
        float4 v4 = yr4[i4];
        float vv[4] = {v4.x, v4.y, v4.z, v4.w};
#pragma unroll
        for (int c = 0; c < 4; ++c) {
            if (f2key(vv[c]) >= keyT) {
                unsigned pos = atomicAdd(&scnt, 1u);
                if (pos < CBUF) cand[(size_t)row * CBUF + pos] = i4 * 4 + c;
            }
        }
    }
    __syncthreads();
    if (tid == 0) ccount[row] = (int)min(scnt, (unsigned)CBUF);
}

// ---------------------------------------------------------------------------
// fp64 refinement: recompute candidate dot products exactly, rank
// (value desc, idx asc), emit final top-16 vals (fp32) + idxs.
// ---------------------------------------------------------------------------
__global__ __launch_bounds__(256) void refine_kernel(
    const float* __restrict__ x,       // [BATCH, D_IN]
    const float* __restrict__ W,       // [D_HID, D_IN]
    const float* __restrict__ bias,    // [D_HID]
    const int* __restrict__ cand,      // [BATCH, CBUF]
    const int* __restrict__ ccount,    // [BATCH]
    float* __restrict__ vals,          // [BATCH, TOPK]
    int* __restrict__ idxs)            // [BATCH, TOPK]
{
    __shared__ float  sx[D_IN];        // 8 KB
    __shared__ double sdot[CBUF];      // 4 KB
    __shared__ int    sidx[CBUF];      // 2 KB
    __shared__ double rdv[256];        // 2 KB
    __shared__ int    rdc[256];        // 1 KB

    const int b = blockIdx.x;
    const int tid = threadIdx.x;
    const int C = ccount[b];

    for (int d = tid; d < D_IN; d += 256) sx[d] = x[(size_t)b * D_IN + d];
    for (int c = tid; c < C; c += 256) sidx[c] = cand[(size_t)b * CBUF + c];
    __syncthreads();

    const int wave = tid >> 6;
    const int lane = tid & 63;
    for (int c = wave; c < C; c += 4) {
        const int h = sidx[c];
        const float* wr = W + (size_t)h * D_IN;
        double acc = 0.0;
        for (int d = lane; d < D_IN; d += 64)
            acc += (double)sx[d] * (double)wr[d];
#pragma unroll
        for (int off = 32; off > 0; off >>= 1)
            acc += __shfl_down(acc, off, 64);
        if (lane == 0) sdot[c] = acc + (double)bias[h];
    }
    __syncthreads();

    for (int k = 0; k < TOPK; ++k) {
        double bv = -1.0e300; int bc = -1;
        for (int c = tid; c < C; c += 256) {
            double v = sdot[c];
            if (v > bv || (v == bv && bc >= 0 && sidx[c] < sidx[bc])) {
                bv = v; bc = c;
            }
        }
        rdv[tid] = bv; rdc[tid] = bc;
        __syncthreads();
        for (int s = 128; s > 0; s >>= 1) {
            if (tid < s) {
                double v2 = rdv[tid + s]; int c2 = rdc[tid + s];
                bool better = (v2 > rdv[tid]) ||
                    (v2 == rdv[tid] && c2 >= 0 &&
                     (rdc[tid] < 0 || sidx[c2] < sidx[rdc[tid]]));
                if (better) { rdv[tid] = v2; rdc[tid] = c2; }
            }
            __syncthreads();
        }
        if (tid == 0) {
            const int wc = rdc[0];
            vals[(size_t)b * TOPK + k] = (float)rdv[0];
            idxs[(size_t)b * TOPK + k] = sidx[wc];
            sdot[wc] = -1.0e300;
        }
        __syncthreads();
    }
}

// ---------------------------------------------------------------------------
// Decode: out[b, :] = sum_k vals[b,k] * W[idx[b,k], :]
// Also writes idx as float into the second output region.
// ---------------------------------------------------------------------------
__global__ __launch_bounds__(256) void decode_kernel(
    const float* __restrict__ vals,
    const int* __restrict__ idxs,
    const float* __restrict__ W,       // [D_HID, D_IN]
    float* __restrict__ out,           // [BATCH, D_IN]
    float* __restrict__ idxOut)        // [BATCH, TOPK] as float
{
    __shared__ float sv[TOPK];
    __shared__ int   si[TOPK];
    const int b = blockIdx.x;
    const int tid = threadIdx.x;

    if (tid < TOPK) {
        float vv = vals[(size_t)b * TOPK + tid];
        int   ii = idxs[(size_t)b * TOPK + tid];
        sv[tid] = vv; si[tid] = ii;
        idxOut[(size_t)b * TOPK + tid] = (float)ii;
    }
    __syncthreads();

    const float4* W4 = (const float4*)W;
    float4* out4 = (float4*)(out + (size_t)b * D_IN);
    for (int d4 = tid; d4 < D_IN / 4; d4 += 256) {
        float4 acc = {0.f, 0.f, 0.f, 0.f};
#pragma unroll
        for (int k = 0; k < TOPK; ++k) {
            float4 w = W4[(size_t)si[k] * (D_IN / 4) + d4];
            float s = sv[k];
            acc.x += s * w.x; acc.y += s * w.y;
            acc.z += s * w.z; acc.w += s * w.w;
        }
        out4[d4] = acc;
    }
}

// ---------------------------------------------------------------------------
extern "C" void kernel_launch(void* const* d_in, const int* in_sizes, int n_in,
                              void* d_out, int out_size, void* d_ws, size_t ws_size,
                              hipStream_t stream)
{
    const float* x    = (const float*)d_in[0];  // [BATCH, D_IN]
    const float* Wenc = (const float*)d_in[1];  // [D_HID, D_IN]
    const float* bias = (const float*)d_in[2];  // [D_HID]
    // d_in[3] = w_emb_w — mathematically Wenc^T, unused.

    float* out    = (float*)d_out;                   // [BATCH, D_IN] fp32
    float* idxOut = out + (size_t)BATCH * D_IN;      // [BATCH, TOPK] as fp32

    char* ws = (char*)d_ws;
    size_t off = 0;
    int*   cand   = (int*)(ws + off);  off += (size_t)BATCH * CBUF * 4;   // 8 MB
    int*   ccount = (int*)(ws + off);  off += (size_t)BATCH * 4;
    float* vals   = (float*)(ws + off); off += (size_t)BATCH * TOPK * 4;
    int*   idxs   = (int*)(ws + off);  off += (size_t)BATCH * TOPK * 4;
    const size_t head = (off + 255) & ~(size_t)255;
    float* ybuf = (float*)(ws + head);

    int chunk = BATCH;
    while (chunk > TM && head + (size_t)chunk * D_HID * 4 > ws_size) chunk >>= 1;

    for (int r0 = 0; r0 < BATCH; r0 += chunk) {
        dim3 g(D_HID / TN, chunk / TM);
        encode_gemm<<<g, 256, 0, stream>>>(x + (size_t)r0 * D_IN, Wenc, bias, ybuf);
        topk_select<<<chunk, 256, 0, stream>>>(ybuf, cand, ccount, r0);
    }
    refine_kernel<<<BATCH, 256, 0, stream>>>(x, Wenc, bias, cand, ccount, vals, idxs);
    decode_kernel<<<BATCH, 256, 0, stream>>>(vals, idxs, Wenc, out, idxOut);
}

// Round 4
// 1178.357 us; speedup vs baseline: 6.3703x; 3.2502x over previous
//
#include <hip/hip_runtime.h>
#include <cfloat>
#include <cstdint>

#define D_IN  2048
#define D_HID 16384
#define TOPK  16
#define BATCH 4096

#define NBINS    4096      // 12-bit histogram: sign + 8 exp + 3 mantissa bits
#define CBUF     512       // candidate cap per row
#define TARGET   32        // min candidates above threshold (margin over 16)

typedef unsigned short ushort_t;
typedef __attribute__((ext_vector_type(8))) short short8;
typedef __attribute__((ext_vector_type(4))) float floatx4;

// ---------------------------------------------------------------------------
// fp32 -> bf16 (RNE) conversion, 8 elements/thread, 16B stores
// ---------------------------------------------------------------------------
__device__ __forceinline__ ushort_t f2bf(float f) {
    unsigned u = __float_as_uint(f);
    u = (u + 0x7FFFu + ((u >> 16) & 1u)) >> 16;
    return (ushort_t)u;
}

__global__ __launch_bounds__(256) void convert_bf16(
    const float* __restrict__ src, ushort_t* __restrict__ dst, int n8)
{
    const int i = blockIdx.x * 256 + threadIdx.x;
    if (i >= n8) return;
    const float4* s4 = (const float4*)src;
    float4 a = s4[2 * i];
    float4 b = s4[2 * i + 1];
    union { ushort_t u[8]; short8 v; } p;
    p.u[0] = f2bf(a.x); p.u[1] = f2bf(a.y); p.u[2] = f2bf(a.z); p.u[3] = f2bf(a.w);
    p.u[4] = f2bf(b.x); p.u[5] = f2bf(b.y); p.u[6] = f2bf(b.z); p.u[7] = f2bf(b.w);
    *(short8*)(dst + (size_t)i * 8) = p.v;
}

// ---------------------------------------------------------------------------
// Coarse encode GEMM, bf16 MFMA (m97 structure):
// y_bf16[M, D_HID] = x_bf16[M, D_IN] * W_bf16[D_HID, D_IN]^T + bias
// 128x128 tile, 4 waves (2x2 of 64x64), 16x16x32 MFMA, BK=32,
// global_load_lds width-16 staging, 2-barrier K-loop.
// ---------------------------------------------------------------------------
#define BK 32

__global__ __launch_bounds__(256) void encode_mfma(
    const ushort_t* __restrict__ A,    // [M, D_IN] bf16 bits (x)
    const ushort_t* __restrict__ B,    // [D_HID, D_IN] bf16 bits (W)
    const float* __restrict__ bias,    // [D_HID]
    ushort_t* __restrict__ Y)          // [M, D_HID] bf16 bits
{
    __shared__ ushort_t As[128 * BK];  // 8 KB, row-major rows of 32 bf16 (64 B)
    __shared__ ushort_t Bs[128 * BK];  // 8 KB

    const int tid = threadIdx.x;
    const int wv = tid >> 6;           // 0..3
    const int ln = tid & 63;
    const int tileM = blockIdx.y * 128;
    const int tileN = blockIdx.x * 128;
    const int waveM = (wv & 1) * 64;
    const int waveN = (wv >> 1) * 64;

    floatx4 acc[4][4] = {};

    // staging: wave wv covers tile rows [wv*32, wv*32+32), 2 issues of 16 rows.
    // lane ln -> row (ln>>2), 16B chunk (ln&3); LDS dest = base + ln*16 (HW rule)
    const int lrow = ln >> 2;
    const int lkof = (ln & 3) * 8;
    const ushort_t* Ag = A + (size_t)(tileM + wv * 32 + lrow) * D_IN + lkof;
    const ushort_t* Bg = B + (size_t)(tileN + wv * 32 + lrow) * D_IN + lkof;
    ushort_t* AsW = As + (wv * 32) * BK;
    ushort_t* BsW = Bs + (wv * 32) * BK;

    // fragment read mapping (verified layouts)
    const int fcol = ln & 15;          // m (A) / n (B) within 16-tile
    const int fk   = (ln >> 4) * 8;    // k offset

    for (int k0 = 0; k0 < D_IN; k0 += BK) {
        __syncthreads();  // previous tile fully consumed
        __builtin_amdgcn_global_load_lds(
            (const __attribute__((address_space(1))) unsigned*)(Ag + k0),
            (__attribute__((address_space(3))) unsigned*)AsW, 16, 0, 0);
        __builtin_amdgcn_global_load_lds(
            (const __attribute__((address_space(1))) unsigned*)(Ag + k0 + (size_t)16 * D_IN),
            (__attribute__((address_space(3))) unsigned*)(AsW + 16 * BK), 16, 0, 0);
        __builtin_amdgcn_global_load_lds(
            (const __attribute__((address_space(1))) unsigned*)(Bg + k0),
            (__attribute__((address_space(3))) unsigned*)BsW, 16, 0, 0);
        __builtin_amdgcn_global_load_lds(
            (const __attribute__((address_space(1))) unsigned*)(Bg + k0 + (size_t)16 * D_IN),
            (__attribute__((address_space(3))) unsigned*)(BsW + 16 * BK), 16, 0, 0);
        __syncthreads();  // vmcnt drained -> tile resident

        short8 af[4], bfr[4];
#pragma unroll
        for (int i = 0; i < 4; ++i)
            af[i] = *(const short8*)(As + (waveM + i * 16 + fcol) * BK + fk);
#pragma unroll
        for (int j = 0; j < 4; ++j)
            bfr[j] = *(const short8*)(Bs + (waveN + j * 16 + fcol) * BK + fk);
#pragma unroll
        for (int i = 0; i < 4; ++i)
#pragma unroll
            for (int j = 0; j < 4; ++j)
                acc[i][j] = __builtin_amdgcn_mfma_f32_16x16x32_bf16(
                    af[i], bfr[j], acc[i][j], 0, 0, 0);
    }

    // epilogue: C/D layout col=lane&15, row=(lane>>4)*4+reg
    const int orow = (ln >> 4) * 4;
    const int ocol = ln & 15;
#pragma unroll
    for (int j = 0; j < 4; ++j) {
        const int gcol = tileN + waveN + j * 16 + ocol;
        const float bc = bias[gcol];
#pragma unroll
        for (int i = 0; i < 4; ++i) {
            const int grow = tileM + waveM + i * 16 + orow;
#pragma unroll
            for (int r = 0; r < 4; ++r)
                Y[(size_t)(grow + r) * D_HID + gcol] = f2bf(acc[i][j][r] + bc);
        }
    }
}

// ---------------------------------------------------------------------------
// Histogram threshold select on bf16 y: emit UNORDERED superset of the
// top-TARGET coarse elements per row (exact ranking by refine_kernel).
// key16 = monotonic 16-bit transform of bf16 bits.
// ---------------------------------------------------------------------------
__device__ __forceinline__ unsigned bf2key(unsigned u) {
    return (u & 0x8000u) ? (~u & 0xFFFFu) : (u | 0x8000u);
}

__global__ __launch_bounds__(256) void topk_select(
    const ushort_t* __restrict__ y,    // [chunkM, D_HID] bf16
    int* __restrict__ cand,            // [BATCH, CBUF]
    int* __restrict__ ccount,          // [BATCH]
    int rowBase)
{
    __shared__ unsigned hist[NBINS];   // 16 KB
    __shared__ unsigned psuf[257];
    __shared__ int sBstar;
    __shared__ unsigned scnt;

    const int tid = threadIdx.x;
    const int row = rowBase + blockIdx.x;
    const short8* yr8 = (const short8*)(y + (size_t)blockIdx.x * D_HID);

    for (int i = tid; i < NBINS; i += 256) hist[i] = 0;
    if (tid == 0) { sBstar = 0; scnt = 0; }
    __syncthreads();

    // Pass 1: histogram of key16 >> 4
    for (int j = 0; j < 8; ++j) {
        union { short8 v; ushort_t u[8]; } p;
        p.v = yr8[tid + j * 256];
#pragma unroll
        for (int c = 0; c < 8; ++c)
            atomicAdd(&hist[bf2key(p.u[c]) >> 4], 1u);
    }
    __syncthreads();

    {
        unsigned s = 0;
#pragma unroll
        for (int i = 0; i < 16; ++i) s += hist[tid * 16 + i];
        psuf[tid] = s;
    }
    __syncthreads();
    if (tid == 0) {
        unsigned run = 0;
        for (int t = 255; t >= 0; --t) { run += psuf[t]; psuf[t] = run; }
        psuf[256] = 0;
    }
    __syncthreads();
    {
        unsigned run = psuf[tid + 1];
        for (int b = tid * 16 + 15; b >= tid * 16; --b) {
            run += hist[b];
            if (run >= TARGET) { atomicMax(&sBstar, b); break; }
        }
    }
    __syncthreads();
    const unsigned keyT = ((unsigned)sBstar) << 4;

    // Pass 2: compact candidate indices (unordered)
    for (int j = 0; j < 8; ++j) {
        const int i8 = tid + j * 256;
        union { short8 v; ushort_t u[8]; } p;
        p.v = yr8[i8];
#pragma unroll
        for (int c = 0; c < 8; ++c) {
            if (bf2key(p.u[c]) >= keyT) {
                unsigned pos = atomicAdd(&scnt, 1u);
                if (pos < CBUF) cand[(size_t)row * CBUF + pos] = i8 * 8 + c;
            }
        }
    }
    __syncthreads();
    if (tid == 0) ccount[row] = (int)min(scnt, (unsigned)CBUF);
}

// ---------------------------------------------------------------------------
// fp64 refinement on the ORIGINAL fp32 inputs: recompute candidate dot
// products exactly, rank (value desc, idx asc), emit top-16 vals + idxs.
// ---------------------------------------------------------------------------
__global__ __launch_bounds__(256) void refine_kernel(
    const float* __restrict__ x,       // [BATCH, D_IN]
    const float* __restrict__ W,       // [D_HID, D_IN]
    const float* __restrict__ bias,    // [D_HID]
    const int* __restrict__ cand,      // [BATCH, CBUF]
    const int* __restrict__ ccount,    // [BATCH]
    float* __restrict__ vals,          // [BATCH, TOPK]
    int* __restrict__ idxs)            // [BATCH, TOPK]
{
    __shared__ float  sx[D_IN];
    __shared__ double sdot[CBUF];
    __shared__ int    sidx[CBUF];
    __shared__ double rdv[256];
    __shared__ int    rdc[256];

    const int b = blockIdx.x;
    const int tid = threadIdx.x;
    const int C = ccount[b];

    for (int d = tid; d < D_IN; d += 256) sx[d] = x[(size_t)b * D_IN + d];
    for (int c = tid; c < C; c += 256) sidx[c] = cand[(size_t)b * CBUF + c];
    __syncthreads();

    const int wave = tid >> 6;
    const int lane = tid & 63;
    for (int c = wave; c < C; c += 4) {
        const int h = sidx[c];
        const float* wr = W + (size_t)h * D_IN;
        double acc = 0.0;
        for (int d = lane; d < D_IN; d += 64)
            acc += (double)sx[d] * (double)wr[d];
#pragma unroll
        for (int off = 32; off > 0; off >>= 1)
            acc += __shfl_down(acc, off, 64);
        if (lane == 0) sdot[c] = acc + (double)bias[h];
    }
    __syncthreads();

    for (int k = 0; k < TOPK; ++k) {
        double bv = -1.0e300; int bc = -1;
        for (int c = tid; c < C; c += 256) {
            double v = sdot[c];
            if (v > bv || (v == bv && bc >= 0 && sidx[c] < sidx[bc])) {
                bv = v; bc = c;
            }
        }
        rdv[tid] = bv; rdc[tid] = bc;
        __syncthreads();
        for (int s = 128; s > 0; s >>= 1) {
            if (tid < s) {
                double v2 = rdv[tid + s]; int c2 = rdc[tid + s];
                bool better = (v2 > rdv[tid]) ||
                    (v2 == rdv[tid] && c2 >= 0 &&
                     (rdc[tid] < 0 || sidx[c2] < sidx[rdc[tid]]));
                if (better) { rdv[tid] = v2; rdc[tid] = c2; }
            }
            __syncthreads();
        }
        if (tid == 0) {
            const int wc = rdc[0];
            vals[(size_t)b * TOPK + k] = (float)rdv[0];
            idxs[(size_t)b * TOPK + k] = sidx[wc];
            sdot[wc] = -1.0e300;
        }
        __syncthreads();
    }
}

// ---------------------------------------------------------------------------
// Decode: out[b, :] = sum_k vals[b,k] * W[idx[b,k], :]  (W = w_enc_w, fp32)
// Also writes idx as float into the second output region.
// ---------------------------------------------------------------------------
__global__ __launch_bounds__(256) void decode_kernel(
    const float* __restrict__ vals,
    const int* __restrict__ idxs,
    const float* __restrict__ W,       // [D_HID, D_IN]
    float* __restrict__ out,           // [BATCH, D_IN]
    float* __restrict__ idxOut)        // [BATCH, TOPK] as float
{
    __shared__ float sv[TOPK];
    __shared__ int   si[TOPK];
    const int b = blockIdx.x;
    const int tid = threadIdx.x;

    if (tid < TOPK) {
        float vv = vals[(size_t)b * TOPK + tid];
        int   ii = idxs[(size_t)b * TOPK + tid];
        sv[tid] = vv; si[tid] = ii;
        idxOut[(size_t)b * TOPK + tid] = (float)ii;
    }
    __syncthreads();

    const float4* W4 = (const float4*)W;
    float4* out4 = (float4*)(out + (size_t)b * D_IN);
    for (int d4 = tid; d4 < D_IN / 4; d4 += 256) {
        float4 acc = {0.f, 0.f, 0.f, 0.f};
#pragma unroll
        for (int k = 0; k < TOPK; ++k) {
            float4 w = W4[(size_t)si[k] * (D_IN / 4) + d4];
            float s = sv[k];
            acc.x += s * w.x; acc.y += s * w.y;
            acc.z += s * w.z; acc.w += s * w.w;
        }
        out4[d4] = acc;
    }
}

// ---------------------------------------------------------------------------
extern "C" void kernel_launch(void* const* d_in, const int* in_sizes, int n_in,
                              void* d_out, int out_size, void* d_ws, size_t ws_size,
                              hipStream_t stream)
{
    const float* x    = (const float*)d_in[0];  // [BATCH, D_IN]
    const float* Wenc = (const float*)d_in[1];  // [D_HID, D_IN]
    const float* bias = (const float*)d_in[2];  // [D_HID]
    // d_in[3] = w_emb_w — mathematically Wenc^T, unused.

    float* out    = (float*)d_out;                   // [BATCH, D_IN] fp32
    float* idxOut = out + (size_t)BATCH * D_IN;      // [BATCH, TOPK] as fp32

    char* ws = (char*)d_ws;
    size_t off = 0;
    int*      cand   = (int*)(ws + off);      off += (size_t)BATCH * CBUF * 4;   // 8 MB
    int*      ccount = (int*)(ws + off);      off += (size_t)BATCH * 4;
    float*    vals   = (float*)(ws + off);    off += (size_t)BATCH * TOPK * 4;
    int*      idxs   = (int*)(ws + off);      off += (size_t)BATCH * TOPK * 4;
    off = (off + 255) & ~(size_t)255;
    ushort_t* xbf    = (ushort_t*)(ws + off); off += (size_t)BATCH * D_IN * 2;   // 16 MB
    ushort_t* wbf    = (ushort_t*)(ws + off); off += (size_t)D_HID * D_IN * 2;   // 64 MB
    const size_t head = (off + 255) & ~(size_t)255;
    ushort_t* ybf = (ushort_t*)(ws + head);

    int chunk = BATCH;
    while (chunk > 128 && head + (size_t)chunk * D_HID * 2 > ws_size) chunk >>= 1;

    const int nx8 = BATCH * D_IN / 8;       // 1,048,576
    const int nw8 = D_HID * D_IN / 8;       // 4,194,304
    convert_bf16<<<(nx8 + 255) / 256, 256, 0, stream>>>(x, xbf, nx8);
    convert_bf16<<<(nw8 + 255) / 256, 256, 0, stream>>>(Wenc, wbf, nw8);

    for (int r0 = 0; r0 < BATCH; r0 += chunk) {
        dim3 g(D_HID / 128, chunk / 128);
        encode_mfma<<<g, 256, 0, stream>>>(xbf + (size_t)r0 * D_IN, wbf, bias, ybf);
        topk_select<<<chunk, 256, 0, stream>>>(ybf, cand, ccount, r0);
    }
    refine_kernel<<<BATCH, 256, 0, stream>>>(x, Wenc, bias, cand, ccount, vals, idxs);
    decode_kernel<<<BATCH, 256, 0, stream>>>(vals, idxs, Wenc, out, idxOut);
}